// Round 1
// baseline (281.630 us; speedup 1.0000x reference)
//
#include <hip/hip_runtime.h>

// Problem constants (match reference): D_IN = D_OUT = 128, SCALING = 100, leaky slope 0.01
#define D 128

__device__ __forceinline__ float rel_w(const float* __restrict__ rel, int t) {
    float v = rel[t] * 100.0f;
    return v > 0.0f ? v : 0.01f * v;   // leaky_relu(rel * scaling)
}

// ---------------- K1: H = X @ W  (f32, per-thread 8x8 register tile) ----------------
// Block: 256 threads; tile: 128 rows x 128 cols. X staged transposed in LDS (stride 132).
__global__ __launch_bounds__(256, 2) void k_gemm(const float* __restrict__ X,
                                                 const float* __restrict__ W,
                                                 float* __restrict__ H, int nrows) {
    __shared__ float sXT[128 * 132];   // [k][r], pad to 132 for conflict-free b128 reads
    const int t = threadIdx.x;
    const int rbase = blockIdx.x * 128;

    // Stage: each thread moves four 4x4 micro-tiles, transposing in registers.
    {
        const int c4 = (t & 31) * 4;          // column base 0..124
        const int rl0 = (t >> 5) * 4;         // 0..28
        #pragma unroll
        for (int bb = 0; bb < 4; ++bb) {
            const int rloc = rl0 + 32 * bb;   // 0..124
            float4 v[4];
            #pragma unroll
            for (int i = 0; i < 4; ++i) {
                const int rr = rbase + rloc + i;
                v[i] = (rr < nrows) ? *(const float4*)&X[(size_t)rr * D + c4]
                                    : make_float4(0.f, 0.f, 0.f, 0.f);
            }
            #pragma unroll
            for (int j = 0; j < 4; ++j) {
                float4 w4;
                w4.x = (&v[0].x)[j]; w4.y = (&v[1].x)[j];
                w4.z = (&v[2].x)[j]; w4.w = (&v[3].x)[j];
                *(float4*)&sXT[(c4 + j) * 132 + rloc] = w4;
            }
        }
    }
    __syncthreads();

    const int jg = t & 15;        // 16 col-groups x 8 cols = 128
    const int rg = t >> 4;        // 16 row-groups x 8 rows = 128
    const int j0 = jg * 8, r0 = rg * 8;

    float acc[8][8] = {};
    #pragma unroll 4
    for (int k = 0; k < 128; ++k) {
        const float4 xa = *(const float4*)&sXT[k * 132 + r0];
        const float4 xb = *(const float4*)&sXT[k * 132 + r0 + 4];
        const float4 wa = *(const float4*)&W[k * D + j0];
        const float4 wb = *(const float4*)&W[k * D + j0 + 4];
        const float xs[8] = {xa.x, xa.y, xa.z, xa.w, xb.x, xb.y, xb.z, xb.w};
        const float ws[8] = {wa.x, wa.y, wa.z, wa.w, wb.x, wb.y, wb.z, wb.w};
        #pragma unroll
        for (int i = 0; i < 8; ++i)
            #pragma unroll
            for (int c = 0; c < 8; ++c)
                acc[i][c] = fmaf(xs[i], ws[c], acc[i][c]);
    }

    #pragma unroll
    for (int i = 0; i < 8; ++i) {
        const int r = rbase + r0 + i;
        if (r < nrows) {
            float4 o0, o1;
            o0.x = acc[i][0]; o0.y = acc[i][1]; o0.z = acc[i][2]; o0.w = acc[i][3];
            o1.x = acc[i][4]; o1.y = acc[i][5]; o1.z = acc[i][6]; o1.w = acc[i][7];
            *(float4*)&H[(size_t)r * D + j0]     = o0;
            *(float4*)&H[(size_t)r * D + j0 + 4] = o1;
        }
    }
}

// ---------------- K2: zero deg / cnt / cur ----------------
__global__ void k_zero(float* __restrict__ deg, int* __restrict__ cnt,
                       int* __restrict__ cur, int n) {
    const int i = blockIdx.x * blockDim.x + threadIdx.x;
    if (i < n) { deg[i] = 0.f; cnt[i] = 0; cur[i] = 0; }
}

// ---------------- K3: per-dst weighted degree + edge counts ----------------
__global__ void k_degcnt(const int* __restrict__ col, const int* __restrict__ et,
                         const float* __restrict__ rel, float* __restrict__ deg,
                         int* __restrict__ cnt, int ne) {
    const int e = blockIdx.x * blockDim.x + threadIdx.x;
    if (e < ne) {
        const int c = col[e];
        atomicAdd(&deg[c], rel_w(rel, et[e]));
        atomicAdd(&cnt[c], 1);
    }
}

// ---------------- K4: exclusive scan of cnt -> offs (3-kernel, chunk=1024) ----------------
__global__ __launch_bounds__(1024) void k_scan1(const int* __restrict__ cnt,
                                                int* __restrict__ offs,
                                                int* __restrict__ bsum, int n) {
    __shared__ int s[1024];
    const int t = threadIdx.x;
    const int i = blockIdx.x * 1024 + t;
    const int v = (i < n) ? cnt[i] : 0;
    s[t] = v;
    __syncthreads();
    int x = v;
    for (int d = 1; d < 1024; d <<= 1) {
        const int y = (t >= d) ? s[t - d] : 0;
        __syncthreads();
        x += y; s[t] = x;
        __syncthreads();
    }
    if (i < n) offs[i] = x - v;          // exclusive within chunk
    if (t == 1023) bsum[blockIdx.x] = x; // chunk total
}

__global__ void k_scan2(int* __restrict__ bsum, int nb) {
    __shared__ int s[128];
    const int t = threadIdx.x;
    const int v = (t < nb) ? bsum[t] : 0;
    s[t] = v;
    __syncthreads();
    int x = v;
    for (int d = 1; d < 128; d <<= 1) {
        const int y = (t >= d) ? s[t - d] : 0;
        __syncthreads();
        x += y; s[t] = x;
        __syncthreads();
    }
    if (t < nb) bsum[t] = x - v;         // exclusive chunk offsets
}

__global__ void k_scan3(int* __restrict__ offs, const int* __restrict__ bsum,
                        int n, int ne) {
    const int i = blockIdx.x * blockDim.x + threadIdx.x;
    if (i < n) offs[i] += bsum[i >> 10];
    if (i == 0) offs[n] = ne;
}

// ---------------- K5: bucket edges by dst (CSR) ----------------
__global__ void k_scatter(const int* __restrict__ col, const int* __restrict__ offs,
                          int* __restrict__ cur, int* __restrict__ order, int ne) {
    const int e = blockIdx.x * blockDim.x + threadIdx.x;
    if (e < ne) {
        const int c = col[e];
        const int p = offs[c] + atomicAdd(&cur[c], 1);
        order[p] = e;
    }
}

// ---------------- K6: one wave per dst node: gather, scale, sum, +bias ----------------
__global__ __launch_bounds__(256) void k_agg(const float* __restrict__ H,
                                             const int* __restrict__ row,
                                             const int* __restrict__ et,
                                             const float* __restrict__ rel,
                                             const float* __restrict__ deg,
                                             const int* __restrict__ offs,
                                             const int* __restrict__ order,
                                             const float* __restrict__ bias,
                                             float* __restrict__ out, int ndst) {
    const int wave = (int)((blockIdx.x * blockDim.x + threadIdx.x) >> 6);
    const int lane = threadIdx.x & 63;
    if (wave >= ndst) return;
    const int d = wave;
    const int beg = offs[d], end = offs[d + 1];

    const float dg = deg[d];
    const float inv = (dg != 0.f) ? 1.0f / dg : 0.f;

    float2 acc = make_float2(0.f, 0.f);
    for (int base = beg; base < end; base += 64) {
        const int idx = base + lane;
        int r = 0; float w = 0.f;
        if (idx < end) {
            const int e = order[idx];
            r = row[e];
            w = rel_w(rel, et[e]) * inv;
        }
        const int c = min(64, end - base);
        for (int i = 0; i < c; ++i) {
            const int   rr = __shfl(r, i);
            const float ww = __shfl(w, i);
            const float2 hv = *(const float2*)&H[(size_t)rr * D + lane * 2];
            acc.x = fmaf(ww, hv.x, acc.x);
            acc.y = fmaf(ww, hv.y, acc.y);
        }
    }

    const float2 b2 = *(const float2*)&bias[lane * 2];
    float2 o;
    o.x = acc.x + b2.x;
    o.y = acc.y + b2.y;
    *(float2*)&out[(size_t)d * D + lane * 2] = o;
}

// ---------------- launch ----------------
extern "C" void kernel_launch(void* const* d_in, const int* in_sizes, int n_in,
                              void* d_out, int out_size, void* d_ws, size_t ws_size,
                              hipStream_t stream) {
    const float* x_src  = (const float*)d_in[0];
    // d_in[1] = x_target: unused ('add' aggregation ignores h_tgt)
    const int*   row    = (const int*)d_in[2];
    const int*   col    = (const int*)d_in[3];
    const int*   etype  = (const int*)d_in[4];
    const float* weight = (const float*)d_in[5];
    const float* bias   = (const float*)d_in[6];
    const float* relw   = (const float*)d_in[7];

    const int nsrc = in_sizes[0] / D;
    const int ndst = out_size / D;
    const int ne   = in_sizes[2];

    // workspace layout (~106.4 MB)
    float* H    = (float*)d_ws;                    // nsrc*D
    float* deg  = H + (size_t)nsrc * D;            // ndst
    int*   cnt  = (int*)(deg + ndst);              // ndst
    int*   offs = cnt + ndst;                      // ndst+1
    int*   cur  = offs + (ndst + 1);               // ndst
    int*   bsum = cur + ndst;                      // up to 256 chunks
    int*   order = bsum + 256;                     // ne

    float* out = (float*)d_out;
    const int nchunk = (ndst + 1023) / 1024;       // 98 for ndst=100000 (<=128)

    hipLaunchKernelGGL(k_gemm, dim3((nsrc + 127) / 128), dim3(256), 0, stream,
                       x_src, weight, H, nsrc);
    hipLaunchKernelGGL(k_zero, dim3((ndst + 255) / 256), dim3(256), 0, stream,
                       deg, cnt, cur, ndst);
    hipLaunchKernelGGL(k_degcnt, dim3((ne + 255) / 256), dim3(256), 0, stream,
                       col, etype, relw, deg, cnt, ne);
    hipLaunchKernelGGL(k_scan1, dim3(nchunk), dim3(1024), 0, stream,
                       cnt, offs, bsum, ndst);
    hipLaunchKernelGGL(k_scan2, dim3(1), dim3(128), 0, stream, bsum, nchunk);
    hipLaunchKernelGGL(k_scan3, dim3((ndst + 255) / 256), dim3(256), 0, stream,
                       offs, bsum, ndst, ne);
    hipLaunchKernelGGL(k_scatter, dim3((ne + 255) / 256), dim3(256), 0, stream,
                       col, offs, cur, order, ne);
    hipLaunchKernelGGL(k_agg, dim3((ndst + 3) / 4), dim3(256), 0, stream,
                       H, row, etype, relw, deg, offs, order, bias, out, ndst);
}

// Round 2
// 189.352 us; speedup vs baseline: 1.4873x; 1.4873x over previous
//
#include <hip/hip_runtime.h>

#define D 128

typedef __attribute__((ext_vector_type(8))) short bf16x8;   // 8 bf16 in 4 VGPRs
typedef __attribute__((ext_vector_type(4))) float f32x4;

__device__ __forceinline__ float rel_w(const float* __restrict__ rel, int t) {
    float v = rel[t] * 100.0f;
    return v > 0.0f ? v : 0.01f * v;   // leaky_relu(rel * scaling)
}

__device__ __forceinline__ ushort f2b(float x) {   // f32 -> bf16 RNE
    unsigned u = __float_as_uint(x);
    u += 0x7FFFu + ((u >> 16) & 1u);
    return (ushort)(u >> 16);
}

// ---------------- K1: zero counters + convert W -> Wt (bf16, transposed [n][k]) ----------
__global__ void k_init(float* __restrict__ deg, int* __restrict__ cnt, int* __restrict__ cur,
                       const float* __restrict__ W, ushort* __restrict__ Wt, int ndst) {
    const int i = blockIdx.x * blockDim.x + threadIdx.x;
    if (i < ndst) { deg[i] = 0.f; cnt[i] = 0; cur[i] = 0; }
    if (i < D * D) {
        const int n = i >> 7, k = i & 127;
        Wt[i] = f2b(W[k * D + n]);     // Wt[n][k] = W[k][n]
    }
}

// ---------------- K2: per-dst weighted degree + edge counts ----------------
__global__ void k_degcnt(const int* __restrict__ col, const int* __restrict__ et,
                         const float* __restrict__ rel, float* __restrict__ deg,
                         int* __restrict__ cnt, int ne) {
    const int e = blockIdx.x * blockDim.x + threadIdx.x;
    if (e < ne) {
        const int c = col[e];
        atomicAdd(&deg[c], rel_w(rel, et[e]));
        atomicAdd(&cnt[c], 1);
    }
}

// ---------------- K3: exclusive scan of cnt -> offs ----------------
__global__ __launch_bounds__(1024) void k_scan1(const int* __restrict__ cnt,
                                                int* __restrict__ offs,
                                                int* __restrict__ bsum, int n) {
    __shared__ int s[1024];
    const int t = threadIdx.x;
    const int i = blockIdx.x * 1024 + t;
    const int v = (i < n) ? cnt[i] : 0;
    s[t] = v;
    __syncthreads();
    int x = v;
    for (int d = 1; d < 1024; d <<= 1) {
        const int y = (t >= d) ? s[t - d] : 0;
        __syncthreads();
        x += y; s[t] = x;
        __syncthreads();
    }
    if (i < n) offs[i] = x - v;
    if (t == 1023) bsum[blockIdx.x] = x;
}

__global__ void k_scan2(int* __restrict__ bsum, int nb) {
    __shared__ int s[128];
    const int t = threadIdx.x;
    const int v = (t < nb) ? bsum[t] : 0;
    s[t] = v;
    __syncthreads();
    int x = v;
    for (int d = 1; d < 128; d <<= 1) {
        const int y = (t >= d) ? s[t - d] : 0;
        __syncthreads();
        x += y; s[t] = x;
        __syncthreads();
    }
    if (t < nb) bsum[t] = x - v;
}

__global__ void k_scan3(int* __restrict__ offs, const int* __restrict__ bsum,
                        int n, int ne) {
    const int i = blockIdx.x * blockDim.x + threadIdx.x;
    if (i < n) offs[i] += bsum[i >> 10];
    if (i == 0) offs[n] = ne;
}

// ---------------- K4: bucket edges by dst (CSR) ----------------
__global__ void k_scatter(const int* __restrict__ col, const int* __restrict__ offs,
                          int* __restrict__ cur, int* __restrict__ order, int ne) {
    const int e = blockIdx.x * blockDim.x + threadIdx.x;
    if (e < ne) {
        const int c = col[e];
        const int p = offs[c] + atomicAdd(&cur[c], 1);
        order[p] = e;
    }
}

// ---------------- K5: one wave per dst: aggregate x_src rows -> bf16 agg row -------------
// 8-deep batched loads: shfl x8, issue 8 independent gathers, then 8 FMAs.
__global__ __launch_bounds__(256) void k_agg(const float* __restrict__ X,
                                             const int* __restrict__ row,
                                             const int* __restrict__ et,
                                             const float* __restrict__ rel,
                                             const float* __restrict__ deg,
                                             const int* __restrict__ offs,
                                             const int* __restrict__ order,
                                             ushort* __restrict__ Ab, int ndst) {
    const int dw = (int)((blockIdx.x * blockDim.x + threadIdx.x) >> 6);
    const int lane = threadIdx.x & 63;
    if (dw >= ndst) return;
    const int beg = offs[dw], end = offs[dw + 1];
    const float dg = deg[dw];
    const float inv = (dg != 0.f) ? 1.0f / dg : 0.f;

    float ax = 0.f, ay = 0.f;
    for (int base = beg; base < end; base += 64) {
        const int idx = base + lane;
        int r = 0; float wv = 0.f;
        if (idx < end) {
            const int e = order[idx];
            r = row[e];
            wv = rel_w(rel, et[e]) * inv;
        }
        const int c = min(64, end - base);
        for (int i0 = 0; i0 < c; i0 += 8) {
            int rr[8]; float ww[8];
            #pragma unroll
            for (int j = 0; j < 8; ++j) {
                rr[j] = __shfl(r, i0 + j);
                ww[j] = __shfl(wv, i0 + j);
            }
            float2 hv[8];
            #pragma unroll
            for (int j = 0; j < 8; ++j)
                hv[j] = *(const float2*)&X[(size_t)rr[j] * D + lane * 2];
            #pragma unroll
            for (int j = 0; j < 8; ++j) {
                ax = fmaf(ww[j], hv[j].x, ax);
                ay = fmaf(ww[j], hv[j].y, ay);
            }
        }
    }
    ushort2 o; o.x = f2b(ax); o.y = f2b(ay);
    *(ushort2*)&Ab[(size_t)dw * D + lane * 2] = o;
}

// ---------------- K6: out = Ab @ W + bias  (bf16 MFMA 16x16x32, f32 out) ----------------
// Block: 256 thr (4 waves), 64 rows x 128 cols. LDS rows padded to 136 bf16 (conflict-free).
__global__ __launch_bounds__(256) void k_mm(const ushort* __restrict__ Ab,
                                            const ushort* __restrict__ Wt,
                                            const float* __restrict__ bias,
                                            float* __restrict__ out, int ndst) {
    __shared__ ushort sW[D * 136];    // [n][k] padded
    __shared__ ushort sA[64 * 136];   // [r][k] padded
    const int t = threadIdx.x;
    const int rbase = blockIdx.x * 64;

    #pragma unroll
    for (int p = 0; p < 8; ++p) {     // stage Wt: 16384 elems, 8 per thread per pass
        const int idx = p * 2048 + t * 8;
        const int n = idx >> 7, k = idx & 127;
        *(bf16x8*)&sW[n * 136 + k] = *(const bf16x8*)&Wt[idx];
    }
    #pragma unroll
    for (int p = 0; p < 4; ++p) {     // stage A: 8192 elems
        const int idx = p * 2048 + t * 8;
        const int r = idx >> 7, k = idx & 127;
        const int gr = rbase + r;
        bf16x8 v = {};
        if (gr < ndst) v = *(const bf16x8*)&Ab[(size_t)gr * D + k];
        *(bf16x8*)&sA[r * 136 + k] = v;
    }
    __syncthreads();

    const int w = t >> 6, l = t & 63;
    const int m16 = l & 15, g4 = l >> 4;          // fragment row/col + k-slot group
    const int arow = w * 16 + m16;

    f32x4 acc[8] = {};
    #pragma unroll
    for (int ks = 0; ks < 4; ++ks) {
        const int k0 = ks * 32 + g4 * 8;
        const bf16x8 a = *(const bf16x8*)&sA[arow * 136 + k0];
        #pragma unroll
        for (int nf = 0; nf < 8; ++nf) {
            const bf16x8 b = *(const bf16x8*)&sW[(nf * 16 + m16) * 136 + k0];
            acc[nf] = __builtin_amdgcn_mfma_f32_16x16x32_bf16(a, b, acc[nf], 0, 0, 0);
        }
    }

    // C/D layout: col = lane&15, row = (lane>>4)*4 + q  [verified m89]
    #pragma unroll
    for (int nf = 0; nf < 8; ++nf) {
        const int colj = nf * 16 + m16;
        const float bv = bias[colj];
        #pragma unroll
        for (int q = 0; q < 4; ++q) {
            const int r = rbase + w * 16 + g4 * 4 + q;
            if (r < ndst) out[(size_t)r * D + colj] = acc[nf][q] + bv;
        }
    }
}

// ---------------- launch ----------------
extern "C" void kernel_launch(void* const* d_in, const int* in_sizes, int n_in,
                              void* d_out, int out_size, void* d_ws, size_t ws_size,
                              hipStream_t stream) {
    const float* x_src  = (const float*)d_in[0];
    const int*   row    = (const int*)d_in[2];
    const int*   col    = (const int*)d_in[3];
    const int*   etype  = (const int*)d_in[4];
    const float* weight = (const float*)d_in[5];
    const float* bias   = (const float*)d_in[6];
    const float* relw   = (const float*)d_in[7];

    const int ndst = out_size / D;
    const int ne   = in_sizes[2];

    // workspace layout (~29 MB)
    ushort* Ab   = (ushort*)d_ws;                  // ndst*128 bf16 (16B-aligned rows)
    ushort* Wt   = Ab + (size_t)ndst * D;          // 16384 bf16
    float*  deg  = (float*)(Wt + D * D);           // ndst
    int*    cnt  = (int*)(deg + ndst);             // ndst
    int*    offs = cnt + ndst;                     // ndst+1
    int*    cur  = offs + (ndst + 1);              // ndst
    int*    bsum = cur + ndst;                     // <=256 chunks
    int*    order = bsum + 256;                    // ne

    float* out = (float*)d_out;
    const int nchunk = (ndst + 1023) / 1024;

    hipLaunchKernelGGL(k_init, dim3((ndst + 255) / 256), dim3(256), 0, stream,
                       deg, cnt, cur, weight, Wt, ndst);
    hipLaunchKernelGGL(k_degcnt, dim3((ne + 255) / 256), dim3(256), 0, stream,
                       col, etype, relw, deg, cnt, ne);
    hipLaunchKernelGGL(k_scan1, dim3(nchunk), dim3(1024), 0, stream,
                       cnt, offs, bsum, ndst);
    hipLaunchKernelGGL(k_scan2, dim3(1), dim3(128), 0, stream, bsum, nchunk);
    hipLaunchKernelGGL(k_scan3, dim3((ndst + 255) / 256), dim3(256), 0, stream,
                       offs, bsum, ndst, ne);
    hipLaunchKernelGGL(k_scatter, dim3((ne + 255) / 256), dim3(256), 0, stream,
                       col, offs, cur, order, ne);
    hipLaunchKernelGGL(k_agg, dim3((ndst + 3) / 4), dim3(256), 0, stream,
                       x_src, row, etype, relw, deg, offs, order, Ab, ndst);
    hipLaunchKernelGGL(k_mm, dim3((ndst + 63) / 64), dim3(256), 0, stream,
                       Ab, Wt, bias, out, ndst);
}

// Round 5
// 161.882 us; speedup vs baseline: 1.7397x; 1.1697x over previous
//
#include <hip/hip_runtime.h>

#define D 128

typedef __attribute__((ext_vector_type(8))) short bf16x8;   // 8 bf16 in 4 VGPRs
typedef __attribute__((ext_vector_type(4))) float f32x4;
typedef __attribute__((ext_vector_type(8))) ushort ushort8;

struct EW { int r; float w; };   // edge record: src row + unnormalized weight

__device__ __forceinline__ float rel_w(const float* __restrict__ rel, int t) {
    float v = rel[t] * 100.0f;
    return v > 0.0f ? v : 0.01f * v;   // leaky_relu(rel * scaling)
}

__device__ __forceinline__ ushort f2b(float x) {   // f32 -> bf16 RNE
    unsigned u = __float_as_uint(x);
    u += 0x7FFFu + ((u >> 16) & 1u);
    return (ushort)(u >> 16);
}

__device__ __forceinline__ float b2f(ushort u) {
    return __uint_as_float((unsigned)u << 16);
}

// ---------------- K1: zero cnt/cur + convert W -> Wt (bf16, transposed [n][k]) ----------
__global__ void k_init(int* __restrict__ cnt, int* __restrict__ cur,
                       const float* __restrict__ W, ushort* __restrict__ Wt, int ndst) {
    const int i = blockIdx.x * blockDim.x + threadIdx.x;
    if (i < ndst) { cnt[i] = 0; cur[i] = 0; }
    if (i < D * D) {
        const int n = i >> 7, k = i & 127;
        Wt[i] = f2b(W[k * D + n]);     // Wt[n][k] = W[k][n]
    }
}

// ---------------- K2: X -> Xb (bf16), streaming convert ----------------
__global__ void k_xb(const float* __restrict__ X, ushort* __restrict__ Xb, int n8) {
    const int i = blockIdx.x * blockDim.x + threadIdx.x;   // one ushort8 chunk
    if (i < n8) {
        const size_t o = (size_t)i * 8;
        const float4 a = *(const float4*)&X[o];
        const float4 b = *(const float4*)&X[o + 4];
        ushort8 v;
        v[0] = f2b(a.x); v[1] = f2b(a.y); v[2] = f2b(a.z); v[3] = f2b(a.w);
        v[4] = f2b(b.x); v[5] = f2b(b.y); v[6] = f2b(b.z); v[7] = f2b(b.w);
        *(ushort8*)&Xb[o] = v;
    }
}

// ---------------- K3: per-dst edge counts (int atomics only) ----------------
__global__ void k_cnt(const int* __restrict__ col, int* __restrict__ cnt, int ne) {
    const int e = blockIdx.x * blockDim.x + threadIdx.x;
    if (e < ne) atomicAdd(&cnt[col[e]], 1);
}

// ---------------- K4: exclusive scan of cnt -> offs ----------------
__global__ __launch_bounds__(1024) void k_scan1(const int* __restrict__ cnt,
                                                int* __restrict__ offs,
                                                int* __restrict__ bsum, int n) {
    __shared__ int s[1024];
    const int t = threadIdx.x;
    const int i = blockIdx.x * 1024 + t;
    const int v = (i < n) ? cnt[i] : 0;
    s[t] = v;
    __syncthreads();
    int x = v;
    for (int d = 1; d < 1024; d <<= 1) {
        const int y = (t >= d) ? s[t - d] : 0;
        __syncthreads();
        x += y; s[t] = x;
        __syncthreads();
    }
    if (i < n) offs[i] = x - v;
    if (t == 1023) bsum[blockIdx.x] = x;
}

__global__ void k_scan2(int* __restrict__ bsum, int nb) {
    __shared__ int s[128];
    const int t = threadIdx.x;
    const int v = (t < nb) ? bsum[t] : 0;
    s[t] = v;
    __syncthreads();
    int x = v;
    for (int d = 1; d < 128; d <<= 1) {
        const int y = (t >= d) ? s[t - d] : 0;
        __syncthreads();
        x += y; s[t] = x;
        __syncthreads();
    }
    if (t < nb) bsum[t] = x - v;
}

__global__ void k_scan3(int* __restrict__ offs, const int* __restrict__ bsum,
                        int n, int ne) {
    const int i = blockIdx.x * blockDim.x + threadIdx.x;
    if (i < n) offs[i] += bsum[i >> 10];
    if (i == 0) offs[n] = ne;
}

// ---------------- K5: bucket edges by dst, materializing (row, w) ----------------
__global__ void k_scatter(const int* __restrict__ col, const int* __restrict__ row,
                          const int* __restrict__ et, const float* __restrict__ rel,
                          const int* __restrict__ offs, int* __restrict__ cur,
                          EW* __restrict__ ewr, int ne) {
    const int e = blockIdx.x * blockDim.x + threadIdx.x;
    if (e < ne) {
        const int c = col[e];
        const int p = offs[c] + atomicAdd(&cur[c], 1);
        EW rec; rec.r = row[e]; rec.w = rel_w(rel, et[e]);
        ewr[p] = rec;
    }
}

// ---------------- K6: one wave per dst: wsum reduce + gather Xb + f32 agg -> bf16 Ab ----
// Round-2 verified structure: 64 lanes per row (ushort2/lane), 8 edges in flight.
__global__ __launch_bounds__(256) void k_agg(const ushort* __restrict__ Xb,
                                             const EW* __restrict__ ewr,
                                             const int* __restrict__ offs,
                                             ushort* __restrict__ Ab, int ndst) {
    const int dw = (int)((blockIdx.x * blockDim.x + threadIdx.x) >> 6);
    const int lane = threadIdx.x & 63;
    if (dw >= ndst) return;
    const int beg = offs[dw], end = offs[dw + 1];

    // pass 1: weighted in-degree via wave reduce (no global atomics)
    float wsum = 0.f;
    for (int base = beg; base < end; base += 64) {
        const int idx = base + lane;
        if (idx < end) wsum += ewr[idx].w;
    }
    #pragma unroll
    for (int s = 1; s < 64; s <<= 1) wsum += __shfl_xor(wsum, s);
    const float inv = (wsum != 0.f) ? 1.f / wsum : 0.f;

    // pass 2: gather + weighted accumulate (f32)
    float ax = 0.f, ay = 0.f;
    for (int base = beg; base < end; base += 64) {
        const int idx = base + lane;
        int r = 0; float wv = 0.f;
        if (idx < end) { EW e = ewr[idx]; r = e.r; wv = e.w * inv; }
        const int c = min(64, end - base);
        for (int i0 = 0; i0 < c; i0 += 8) {
            int rr[8]; float ww[8];
            #pragma unroll
            for (int j = 0; j < 8; ++j) {
                rr[j] = __shfl(r, i0 + j);
                ww[j] = __shfl(wv, i0 + j);
            }
            ushort2 hv[8];
            #pragma unroll
            for (int j = 0; j < 8; ++j)
                hv[j] = *(const ushort2*)&Xb[(size_t)rr[j] * D + lane * 2];
            #pragma unroll
            for (int j = 0; j < 8; ++j) {
                ax = fmaf(ww[j], b2f(hv[j].x), ax);
                ay = fmaf(ww[j], b2f(hv[j].y), ay);
            }
        }
    }
    ushort2 o; o.x = f2b(ax); o.y = f2b(ay);
    *(ushort2*)&Ab[(size_t)dw * D + lane * 2] = o;
}

// ---------------- K7: out = Ab @ W + bias  (bf16 MFMA 16x16x32, f32 out) ----------------
// Verbatim round-2 k_mm (hardware-verified). 64 rows x 128 cols per 256-thr block.
__global__ __launch_bounds__(256) void k_mm(const ushort* __restrict__ Ab,
                                            const ushort* __restrict__ Wt,
                                            const float* __restrict__ bias,
                                            float* __restrict__ out, int ndst) {
    __shared__ ushort sW[D * 136];    // [n][k] padded
    __shared__ ushort sA[64 * 136];   // [r][k] padded
    const int t = threadIdx.x;
    const int rbase = blockIdx.x * 64;

    #pragma unroll
    for (int p = 0; p < 8; ++p) {     // stage Wt: 16384 elems
        const int idx = p * 2048 + t * 8;
        const int n = idx >> 7, k = idx & 127;
        *(bf16x8*)&sW[n * 136 + k] = *(const bf16x8*)&Wt[idx];
    }
    #pragma unroll
    for (int p = 0; p < 4; ++p) {     // stage A: 8192 elems
        const int idx = p * 2048 + t * 8;
        const int r = idx >> 7, k = idx & 127;
        const int gr = rbase + r;
        bf16x8 v = {};
        if (gr < ndst) v = *(const bf16x8*)&Ab[(size_t)gr * D + k];
        *(bf16x8*)&sA[r * 136 + k] = v;
    }
    __syncthreads();

    const int w = t >> 6, l = t & 63;
    const int m16 = l & 15, g4 = l >> 4;
    const int arow = w * 16 + m16;

    f32x4 acc[8] = {};
    #pragma unroll
    for (int ks = 0; ks < 4; ++ks) {
        const int k0 = ks * 32 + g4 * 8;
        const bf16x8 a = *(const bf16x8*)&sA[arow * 136 + k0];
        #pragma unroll
        for (int nf = 0; nf < 8; ++nf) {
            const bf16x8 b = *(const bf16x8*)&sW[(nf * 16 + m16) * 136 + k0];
            acc[nf] = __builtin_amdgcn_mfma_f32_16x16x32_bf16(a, b, acc[nf], 0, 0, 0);
        }
    }

    // C/D layout: col = lane&15, row = (lane>>4)*4 + q
    #pragma unroll
    for (int nf = 0; nf < 8; ++nf) {
        const int colj = nf * 16 + m16;
        const float bv = bias[colj];
        #pragma unroll
        for (int q = 0; q < 4; ++q) {
            const int r = rbase + w * 16 + g4 * 4 + q;
            if (r < ndst) out[(size_t)r * D + colj] = acc[nf][q] + bv;
        }
    }
}

// ---------------- launch ----------------
extern "C" void kernel_launch(void* const* d_in, const int* in_sizes, int n_in,
                              void* d_out, int out_size, void* d_ws, size_t ws_size,
                              hipStream_t stream) {
    const float* x_src  = (const float*)d_in[0];
    const int*   row    = (const int*)d_in[2];
    const int*   col    = (const int*)d_in[3];
    const int*   etype  = (const int*)d_in[4];
    const float* weight = (const float*)d_in[5];
    const float* bias   = (const float*)d_in[6];
    const float* relw   = (const float*)d_in[7];

    const int nsrc = in_sizes[0] / D;
    const int ndst = out_size / D;
    const int ne   = in_sizes[2];

    // workspace (~84 MB)
    ushort* Xb   = (ushort*)d_ws;                   // nsrc*D bf16 (51.2 MB)
    ushort* Ab   = Xb + (size_t)nsrc * D;           // ndst*D bf16 (25.6 MB)
    ushort* Wt   = Ab + (size_t)ndst * D;           // D*D bf16
    EW*     ewr  = (EW*)(Wt + D * D);               // ne (8B records, 4.8 MB)
    int*    cnt  = (int*)(ewr + ne);                // ndst
    int*    offs = cnt + ndst;                      // ndst+1
    int*    cur  = offs + (ndst + 1);               // ndst
    int*    bsum = cur + ndst;                      // <=256

    float* out = (float*)d_out;
    const int nchunk = (ndst + 1023) / 1024;
    const int n8 = nsrc * D / 8;                    // ushort8 chunks in X

    hipLaunchKernelGGL(k_init, dim3((ndst + 255) / 256), dim3(256), 0, stream,
                       cnt, cur, weight, Wt, ndst);
    hipLaunchKernelGGL(k_xb, dim3((n8 + 255) / 256), dim3(256), 0, stream,
                       x_src, Xb, n8);
    hipLaunchKernelGGL(k_cnt, dim3((ne + 255) / 256), dim3(256), 0, stream,
                       col, cnt, ne);
    hipLaunchKernelGGL(k_scan1, dim3(nchunk), dim3(1024), 0, stream,
                       cnt, offs, bsum, ndst);
    hipLaunchKernelGGL(k_scan2, dim3(1), dim3(128), 0, stream, bsum, nchunk);
    hipLaunchKernelGGL(k_scan3, dim3((ndst + 255) / 256), dim3(256), 0, stream,
                       offs, bsum, ndst, ne);
    hipLaunchKernelGGL(k_scatter, dim3((ne + 255) / 256), dim3(256), 0, stream,
                       col, row, etype, relw, offs, cur, ewr, ne);
    hipLaunchKernelGGL(k_agg, dim3((ndst + 3) / 4), dim3(256), 0, stream,
                       Xb, ewr, offs, Ab, ndst);
    hipLaunchKernelGGL(k_mm, dim3((ndst + 63) / 64), dim3(256), 0, stream,
                       Ab, Wt, bias, out, ndst);
}